// Round 8
// baseline (137.890 us; speedup 1.0000x reference)
//
#include <hip/hip_runtime.h>

#define IN_DIM   256
#define OUT_DIM  256
#define NKNOT    19                    // NUM_KNOTS-1 spline segments
#define NCOL     (IN_DIM * NKNOT)      // 4864 (i,k) columns
#define CPQ      1216                  // columns per i-quarter (64*19)
#define SLICE_E  (CPQ * 64)            // 77824 entries per (quarter,o_half) slice
#define EG_SLICE (64 * 2 * 64)         // edge-table entries per slice
#define OCAP     32768                 // outlier list capacity
#define X_MIN_C  (-5.0f)
#define X_MAX_C  (5.0f)
#define H_C      (10.0f / 19.0f)
#define INV_H_C  (19.0f / 10.0f)

typedef __fp16 half2_t __attribute__((ext_vector_type(2)));
typedef float  f32x2  __attribute__((ext_vector_type(2)));

// pack two f32 -> f16 pair (RTZ), low = x, high = y  (v_cvt_pkrtz_f16_f32)
__device__ __forceinline__ unsigned int pk_f16(float x, float y) {
    return __builtin_bit_cast(unsigned int, __builtin_amdgcn_cvt_pkrtz(x, y));
}
__device__ __forceinline__ float lo_f16(unsigned int u) {
    return (float)__builtin_bit_cast(half2_t, u).x;
}
__device__ __forceinline__ float hi_f16(unsigned int u) {
    return (float)__builtin_bit_cast(half2_t, u).y;
}

// acc += w.lo*c.lo + w.hi*c.hi   (v_dot2_f32_f16, f32 accumulate)
__device__ __forceinline__ float fdot2(unsigned int w, unsigned int c, float acc) {
#if __has_builtin(__builtin_amdgcn_fdot2)
    return __builtin_amdgcn_fdot2(__builtin_bit_cast(half2_t, w),
                                  __builtin_bit_cast(half2_t, c), acc, false);
#else
    half2_t a = __builtin_bit_cast(half2_t, w);
    half2_t b = __builtin_bit_cast(half2_t, c);
    return acc + (float)a.x * (float)b.x + (float)a.y * (float)b.y;
#endif
}

// ---- fp8 e4m3 pack/unpack; word-select is a COMPILE-TIME constant ----
#if __has_builtin(__builtin_amdgcn_cvt_pk_fp8_f32)
template <bool HI>
__device__ __forceinline__ unsigned int pk2_fp8(float x, float y, unsigned int old) {
    return (unsigned int)__builtin_amdgcn_cvt_pk_fp8_f32(x, y, (int)old, HI);
}
#else
__device__ __forceinline__ unsigned int enc1_fp8(float v) {
    v = fminf(fmaxf(v, -448.f), 448.f);
    unsigned u = __float_as_uint(v);
    unsigned s = u >> 31;
    int e = (int)((u >> 23) & 255) - 127;
    unsigned m = u & 0x7fffff;
    if (e < -9) return s << 7;
    if (e < -6) {                       // subnormal, unit 2^-9
        unsigned full = m | 0x800000;
        int sh = 23 - (e + 9);
        unsigned q = full >> sh, rem = full & ((1u << sh) - 1);
        q += (rem > (1u << (sh - 1))) || (rem == (1u << (sh - 1)) && (q & 1));
        return (s << 7) | q;
    }
    unsigned q = m >> 20, rem = m & 0xFFFFF;
    q += (rem > 0x80000) || (rem == 0x80000 && (q & 1));
    return (s << 7) | ((((unsigned)(e + 7)) << 3) + q);
}
template <bool HI>
__device__ __forceinline__ unsigned int pk2_fp8(float x, float y, unsigned int old) {
    unsigned p = enc1_fp8(x) | (enc1_fp8(y) << 8);
    return HI ? ((old & 0xFFFFu) | (p << 16)) : ((old & 0xFFFF0000u) | p);
}
#endif

#if __has_builtin(__builtin_amdgcn_cvt_pk_f32_fp8)
template <bool HI>
__device__ __forceinline__ f32x2 up2_fp8(unsigned int w) {
    return __builtin_amdgcn_cvt_pk_f32_fp8((int)w, HI);
}
#else
__device__ __forceinline__ float dec1_fp8(unsigned b) {
    unsigned s = (b >> 7) & 1, e = (b >> 3) & 15, m = b & 7;
    float mag = e ? __uint_as_float(((e + 120) << 23) | (m << 20))
                  : (float)m * 0.001953125f;            // 2^-9
    return s ? -mag : mag;
}
template <bool HI>
__device__ __forceinline__ f32x2 up2_fp8(unsigned int w) {
    unsigned h = HI ? (w >> 16) : (w & 0xFFFFu);
    f32x2 r; r.x = dec1_fp8(h & 0xFF); r.y = dec1_fp8(h >> 8);
    return r;
}
#endif

// ---------------------------------------------------------------------------
// Kernel 1: transpose + pack. coeffs [o=256][c=4864] float4 ->
//  AB slice (uint2): { pk_f16(a,b) o-even, o-odd }      (8 B / o-pair)
//  CD slice (uint):  { fp8(c,d) o-even | o-odd }        (4 B / o-pair)
//  Eg edge table (uint2): f16 (c,d) for k in {0,18} only — outlier patch data.
//  Also zeroes the outlier counter.
// ---------------------------------------------------------------------------
__global__ __launch_bounds__(256) void transpose_pack(
        const float4* __restrict__ src,
        uint2* __restrict__ AB, unsigned int* __restrict__ CD,
        uint2* __restrict__ Eg, int* __restrict__ ocount) {
    if (blockIdx.x == 0 && threadIdx.x == 0) ocount[0] = 0;

    __shared__ float4 tile[64][65];          // [c_local][o_local], +1 pad
    const int c0 = (blockIdx.x % 76) * 64;   // no quarter straddle: 1216 % 64 == 0
    const int r0 = (blockIdx.x / 76) * 64;   // o-tile base
    const int tx = threadIdx.x & 63;
    const int ty = threadIdx.x >> 6;

    #pragma unroll
    for (int jj = 0; jj < 16; ++jj) {
        const int r = ty * 16 + jj;
        tile[tx][r] = src[(size_t)(r0 + r) * NCOL + (size_t)(c0 + tx)];
    }
    __syncthreads();

    const int quarter  = c0 / CPQ;
    const int clbase   = c0 - quarter * CPQ;
    const int o_half   = r0 >> 7;
    const int og2_base = (r0 & 127) >> 1;    // 0 or 32
    const int slice    = quarter * 2 + o_half;
    uint2*        bAB = AB + (size_t)slice * SLICE_E;
    unsigned int* bCD = CD + (size_t)slice * SLICE_E;
    uint2*        bEg = Eg + (size_t)slice * EG_SLICE;

    #pragma unroll
    for (int jj = 0; jj < 8; ++jj) {
        const int p    = jj * 256 + threadIdx.x;
        const int cl   = p >> 5;             // 0..63
        const int og2l = p & 31;             // 0..31
        const float4 v0 = tile[cl][og2l * 2];      // o even: a,b,c,d
        const float4 v1 = tile[cl][og2l * 2 + 1];  // o odd
        uint2 ab;
        ab.x = pk_f16(v0.x, v0.y);           // (a,b) o-even
        ab.y = pk_f16(v1.x, v1.y);           // (a,b) o-odd
        unsigned int cd = pk2_fp8<false>(v0.z, v0.w, 0u);
        cd = pk2_fp8<true>(v1.z, v1.w, cd);
        const int colq = clbase + cl;        // (i_loc*19 + k) within quarter
        const size_t e = (size_t)colq * 64 + og2_base + og2l;
        bAB[e] = ab;
        bCD[e] = cd;
        const int kk = colq % 19;
        if (kk == 0 || kk == 18) {           // edge segment: exact f16 (c,d)
            const int i_loc = colq / 19;
            const int ke = kk ? 1 : 0;
            bEg[(i_loc * 2 + ke) * 64 + og2_base + og2l] =
                make_uint2(pk_f16(v0.z, v0.w), pk_f16(v1.z, v1.w));
        }
    }
}

// ---------------------------------------------------------------------------
// Kernel 2: partial gather+eval (r2 structure, 12 B/pair). 256 thr = 4 bs x
//  64 og2; thread owns 2 o's. Per i: LDS broadcast + dwordx2 (AB) + dword
//  (CD) = 12 dense lines/wave vs 16. Staging appends |x|>5 outliers (o_half 0
//  blocks only) for the sparse fp8 correction pass.
// ---------------------------------------------------------------------------
__global__ __launch_bounds__(256, 4) void kan_partial(
        const float* __restrict__ x,
        const uint2* __restrict__ AB,
        const unsigned int* __restrict__ CD,
        float2*      __restrict__ part,     // float layout: [4][B][256] linear o
        int*         __restrict__ ocount,
        int*         __restrict__ olist,
        int B) {
    __shared__ int4 s_tk[4 * 64];           // {k*64, pk(1,t), t2 bits, t3 bits}

    const int s       = blockIdx.x & 7;
    const int o_half  = s & 1;
    const int quarter = s >> 1;
    const int bgrp    = blockIdx.x >> 3;
    const int tid     = threadIdx.x;

    {
        const int col = tid & 63;
        const int row = tid >> 6;
        const int b   = bgrp * 4 + row;
        const int i   = quarter * 64 + col;
        const float xv = x[b * IN_DIM + i];
        const float f  = (xv - X_MIN_C) * INV_H_C;
        int idx = (int)floorf(f);
        idx = idx < 0 ? 0 : (idx > NKNOT - 1 ? NKNOT - 1 : idx);
        const float t  = xv - (X_MIN_C + (float)idx * H_C);
        const float t2 = t * t;
        s_tk[row * 64 + col] = make_int4(idx * 64,
                                        (int)pk_f16(1.0f, t),
                                        __float_as_int(t2),
                                        __float_as_int(t2 * t));
        if (o_half == 0 && (xv < X_MIN_C || xv > X_MAX_C)) {
            const int slot = atomicAdd(ocount, 1);
            if (slot < OCAP) olist[slot] = (b << 8) | i;
        }
    }
    __syncthreads();

    const int og2 = tid & 63;
    const int bs  = tid >> 6;
    const uint2*        baseAB = AB + (size_t)s * SLICE_E + og2;
    const unsigned int* baseCD = CD + (size_t)s * SLICE_E + og2;
    const int4* tkp = s_tk + bs * 64;

    float y0 = 0.f, y1 = 0.f;

    #pragma unroll 8
    for (int ii = 0; ii < 64; ++ii) {
        const int4 tk = tkp[ii];                     // wave-uniform broadcast
        const int  e  = ii * 1216 + tk.x;            // (ii*19 + k) * 64
        const uint2        ab  = baseAB[e];
        const unsigned int cdw = baseCD[e];
        const unsigned int w01 = (unsigned int)tk.y; // (1, t) f16
        const float t2 = __int_as_float(tk.z);
        const float t3 = __int_as_float(tk.w);
        const f32x2 cd0 = up2_fp8<false>(cdw);       // (c,d) o-even
        const f32x2 cd1 = up2_fp8<true>(cdw);        // (c,d) o-odd
        y0 = fdot2(w01, ab.x, y0);                   // a + b t
        y1 = fdot2(w01, ab.y, y1);
        y0 += cd0.x * t2 + cd0.y * t3;
        y1 += cd1.x * t2 + cd1.y * t3;
    }

    const int b = bgrp * 4 + bs;
    part[(size_t)quarter * (B * 128) + (size_t)b * 128 + o_half * 64 + og2] =
        make_float2(y0, y1);
}

// ---------------------------------------------------------------------------
// Kernel 2b: sparse outlier correction. For each listed (b,i) (|x|>5, edge
//  segment, huge t), replace the fp8 (c,d) contribution with exact f16 via
//  delta-atomics into part. ~3.3K entries -> negligible traffic.
//  128 threads handle one entry (2 o_half x 64 og2); 2 entries per block.
// ---------------------------------------------------------------------------
__global__ __launch_bounds__(256) void kan_correct(
        const float* __restrict__ x,
        const unsigned int* __restrict__ CD,
        const uint2* __restrict__ Eg,
        float* __restrict__ part,
        const int* __restrict__ ocount,
        const int* __restrict__ olist,
        int B) {
    const int half   = threadIdx.x >> 7;     // 0/1: entry sub-slot
    const int lt     = threadIdx.x & 127;
    const int o_half = lt >> 6;
    const int og2    = lt & 63;
    const int count  = min(ocount[0], OCAP);

    for (int e = blockIdx.x * 2 + half; e < count; e += gridDim.x * 2) {
        const int be = olist[e];
        const int b = be >> 8, i = be & 255;
        const float xv = x[b * IN_DIM + i];
        const float f  = (xv - X_MIN_C) * INV_H_C;
        int idx = (int)floorf(f);
        idx = idx < 0 ? 0 : (idx > NKNOT - 1 ? NKNOT - 1 : idx);
        const float t  = xv - (X_MIN_C + (float)idx * H_C);
        const float t2 = t * t;
        const float t3 = t2 * t;
        const int quarter = i >> 6, i_loc = i & 63;
        const int ke = idx ? 1 : 0;
        const int s  = quarter * 2 + o_half;
        const uint2 cdh = Eg[(size_t)s * EG_SLICE + (i_loc * 2 + ke) * 64 + og2];
        const unsigned int cdw = CD[(size_t)s * SLICE_E +
                                    (size_t)(i_loc * 19 + idx) * 64 + og2];
        const f32x2 q0 = up2_fp8<false>(cdw);
        const f32x2 q1 = up2_fp8<true>(cdw);
        const float D0 = (lo_f16(cdh.x) - q0.x) * t2 + (hi_f16(cdh.x) - q0.y) * t3;
        const float D1 = (lo_f16(cdh.y) - q1.x) * t2 + (hi_f16(cdh.y) - q1.y) * t3;
        float* pp = part + ((size_t)quarter * (B * 128) +
                            (size_t)b * 128 + o_half * 64 + og2) * 2;
        atomicAdd(pp,     D0);
        atomicAdd(pp + 1, D1);
    }
}

// ---------------------------------------------------------------------------
// Kernel 3: out = sum of 4 quarter-partials + bias  (float4) — unchanged.
// ---------------------------------------------------------------------------
__global__ __launch_bounds__(256) void kan_reduce(
        const float4* __restrict__ part,
        const float4* __restrict__ bias4,
        float4*       __restrict__ out,
        int n4) {
    const int n = blockIdx.x * 256 + threadIdx.x;
    if (n < n4) {
        const float4 p0 = part[n];
        const float4 p1 = part[n4 + n];
        const float4 p2 = part[2 * n4 + n];
        const float4 p3 = part[3 * n4 + n];
        const float4 bv = bias4[n & 63];
        float4 r;
        r.x = (p0.x + p1.x) + (p2.x + p3.x) + bv.x;
        r.y = (p0.y + p1.y) + (p2.y + p3.y) + bv.y;
        r.z = (p0.z + p1.z) + (p2.z + p3.z) + bv.z;
        r.w = (p0.w + p1.w) + (p2.w + p3.w) + bv.w;
        out[n] = r;
    }
}

// ---------------------------------------------------------------------------
extern "C" void kernel_launch(void* const* d_in, const int* in_sizes, int n_in,
                              void* d_out, int out_size, void* d_ws, size_t ws_size,
                              hipStream_t stream) {
    const float* x      = (const float*)d_in[0];   // (B, 256) fp32
    const float* coeffs = (const float*)d_in[1];   // (256, 256, 19, 4) fp32
    const float* bias   = (const float*)d_in[2];   // (256,) fp32
    float*       out    = (float*)d_out;           // (B, 256) fp32

    const int B = in_sizes[0] / IN_DIM;            // 1024
    uint2*        AB   = (uint2*)d_ws;                              // 4.98 MB
    unsigned int* CD   = (unsigned int*)((char*)d_ws + (6u << 20)); // 2.49 MB
    uint2*        Eg   = (uint2*)((char*)d_ws + (9u << 20));        // 512 KB
    float*        part = (float*)((char*)d_ws + (10u << 20));       // 4 MB
    int*          ocnt = (int*)((char*)d_ws + (14u << 20));         // counter
    int*          olst = ocnt + 16;                                 // list

    transpose_pack<<<304, 256, 0, stream>>>((const float4*)coeffs, AB, CD, Eg, ocnt);

    kan_partial<<<(B / 4) * 8, 256, 0, stream>>>(x, AB, CD, (float2*)part,
                                                 ocnt, olst, B);

    kan_correct<<<128, 256, 0, stream>>>(x, CD, Eg, part, ocnt, olst, B);

    const int n4 = B * OUT_DIM / 4;                // B*64
    kan_reduce<<<(n4 + 255) / 256, 256, 0, stream>>>(
        (const float4*)part, (const float4*)bias, (float4*)out, n4);
}

// Round 9
// 93.909 us; speedup vs baseline: 1.4683x; 1.4683x over previous
//
#include <hip/hip_runtime.h>

#define IN_DIM   256
#define OUT_DIM  256
#define NKNOT    19                    // NUM_KNOTS-1 spline segments
#define NCOL     (IN_DIM * NKNOT)      // 4864 (i,k) columns
#define CPQ      1216                  // columns per i-quarter (64*19)
#define SLICE_U4 (CPQ * 64)            // 77824 uint4 per (quarter,o_half) slice
#define X_MIN_C  (-5.0f)
#define H_C      (10.0f / 19.0f)
#define INV_H_C  (19.0f / 10.0f)

typedef __fp16 half2_t __attribute__((ext_vector_type(2)));

// pack two f32 -> f16 pair (RTZ), low = x, high = y  (v_cvt_pkrtz_f16_f32)
__device__ __forceinline__ unsigned int pk_f16(float x, float y) {
    return __builtin_bit_cast(unsigned int, __builtin_amdgcn_cvt_pkrtz(x, y));
}

// acc += w.lo*c.lo + w.hi*c.hi   (v_dot2_f32_f16, f32 accumulate)
__device__ __forceinline__ float fdot2(unsigned int w, unsigned int c, float acc) {
#if __has_builtin(__builtin_amdgcn_fdot2)
    return __builtin_amdgcn_fdot2(__builtin_bit_cast(half2_t, w),
                                  __builtin_bit_cast(half2_t, c), acc, false);
#else
    half2_t a = __builtin_bit_cast(half2_t, w);
    half2_t b = __builtin_bit_cast(half2_t, c);
    return acc + (float)a.x * (float)b.x + (float)a.y * (float)b.y;
#endif
}

// ---------------------------------------------------------------------------
// Kernel 1: transpose + pack to f16.  (identical to round-2 baseline)
//  coeffs [o=256][c=4864] float4 -> per-slice uint4 entries:
//   slice s = quarter*2 + o_half;  entry (i_loc*19 + k)*64 + og2:
//   Q = { pk(a,b), pk(c,d) } of o = o_half*128 + 2*og2  |  same of o+1.
// ---------------------------------------------------------------------------
__global__ __launch_bounds__(256) void transpose_pack(
        const float4* __restrict__ src, uint4* __restrict__ dst) {
    __shared__ uint2 tile[64][65];           // [c_local][o_local] f16 quads, +1 pad
    const int c0 = (blockIdx.x % 76) * 64;   // no quarter straddle: 1216 % 64 == 0
    const int r0 = (blockIdx.x / 76) * 64;   // o-tile base
    const int tx = threadIdx.x & 63;
    const int ty = threadIdx.x >> 6;

    #pragma unroll
    for (int jj = 0; jj < 16; ++jj) {
        const int r = ty * 16 + jj;
        const float4 v = src[(size_t)(r0 + r) * NCOL + (size_t)(c0 + tx)];
        uint2 p;
        p.x = pk_f16(v.x, v.y);              // (a,b)
        p.y = pk_f16(v.z, v.w);              // (c,d)
        tile[tx][r] = p;
    }
    __syncthreads();

    const int quarter  = c0 / CPQ;
    const int clbase   = c0 - quarter * CPQ;
    const int o_half   = r0 >> 7;
    const int og2_base = (r0 & 127) >> 1;    // 0 or 32
    uint4* base = dst + (size_t)(quarter * 2 + o_half) * SLICE_U4;

    #pragma unroll
    for (int jj = 0; jj < 8; ++jj) {
        const int p     = jj * 256 + threadIdx.x;
        const int cl    = p >> 5;            // 0..63
        const int og2l  = p & 31;            // 0..31
        const uint2 t0  = tile[cl][og2l * 2];      // o even
        const uint2 t1  = tile[cl][og2l * 2 + 1];  // o odd
        base[(size_t)(clbase + cl) * 64 + og2_base + og2l] =
            make_uint4(t0.x, t0.y, t1.x, t1.y);
    }
}

// ---------------------------------------------------------------------------
// Kernel 2: partial gather+eval — r2 structure, but with an EXPLICIT 8-deep
//  register prefetch pipeline. Fully unrolled so q[]/w[] indices are static
//  (no scratch). ~8 outstanding 1 KB wave-loads instead of the compiler's
//  2-3 at VGPR=36 -> hides L2 gather latency.
//  grid = 8 slices x B/4 bgrps = 2048 blocks.
// ---------------------------------------------------------------------------
__global__ __launch_bounds__(256, 4) void kan_partial(
        const float* __restrict__ x,
        const uint4* __restrict__ Ct,
        float2*      __restrict__ part,     // float layout: [4][B][256] linear o
        int B) {
    __shared__ int4 s_tk[4 * 64];           // {k*64, pk(1,t), pk(t2,t3), 0}

    const int s       = blockIdx.x & 7;
    const int o_half  = s & 1;
    const int quarter = s >> 1;
    const int bgrp    = blockIdx.x >> 3;
    const int tid     = threadIdx.x;

    {
        const int col = tid & 63;
        const int row = tid >> 6;
        const float xv = x[(bgrp * 4 + row) * IN_DIM + quarter * 64 + col];
        const float f  = (xv - X_MIN_C) * INV_H_C;
        int idx = (int)floorf(f);
        idx = idx < 0 ? 0 : (idx > NKNOT - 1 ? NKNOT - 1 : idx);
        const float t  = xv - (X_MIN_C + (float)idx * H_C);
        const float t2 = t * t;
        const float t3 = t2 * t;
        s_tk[row * 64 + col] = make_int4(idx * 64,
                                        (int)pk_f16(1.0f, t),
                                        (int)pk_f16(t2, t3), 0);
    }
    __syncthreads();

    const int og2 = tid & 63;
    const int bs  = tid >> 6;
    const uint4* base = Ct + (size_t)s * SLICE_U4 + og2;   // fold og2 into base
    const int4* tkp = s_tk + bs * 64;

    // ---- 8-deep software pipeline: q = data, wA/wB = (1,t)/(t2,t3) f16 ----
    uint4 q[8];
    unsigned int wA[8], wB[8];
    #pragma unroll
    for (int p = 0; p < 8; ++p) {
        const int4 tk = tkp[p];
        q[p]  = base[p * 1216 + tk.x];
        wA[p] = (unsigned int)tk.y;
        wB[p] = (unsigned int)tk.z;
    }

    float y0 = 0.f, y1 = 0.f;

    #pragma unroll
    for (int ii = 0; ii < 64; ++ii) {
        const int j = ii & 7;                // static after full unroll
        const uint4        Q   = q[j];
        const unsigned int w01 = wA[j];
        const unsigned int w23 = wB[j];
        if (ii < 56) {                       // compile-time predicate
            const int4 tk = tkp[ii + 8];
            q[j]  = base[(ii + 8) * 1216 + tk.x];
            wA[j] = (unsigned int)tk.y;
            wB[j] = (unsigned int)tk.z;
        }
        y0 = fdot2(w01, Q.x, y0);            // a + b t      (o even)
        y0 = fdot2(w23, Q.y, y0);            // c t^2 + d t^3
        y1 = fdot2(w01, Q.z, y1);            // (o odd)
        y1 = fdot2(w23, Q.w, y1);
    }

    const int b = bgrp * 4 + bs;
    part[(size_t)quarter * (B * 128) + (size_t)b * 128 + o_half * 64 + og2] =
        make_float2(y0, y1);
}

// ---------------------------------------------------------------------------
// Kernel 3: out = sum of 4 quarter-partials + bias  (float4) — unchanged.
// ---------------------------------------------------------------------------
__global__ __launch_bounds__(256) void kan_reduce(
        const float4* __restrict__ part,
        const float4* __restrict__ bias4,
        float4*       __restrict__ out,
        int n4) {
    const int n = blockIdx.x * 256 + threadIdx.x;
    if (n < n4) {
        const float4 p0 = part[n];
        const float4 p1 = part[n4 + n];
        const float4 p2 = part[2 * n4 + n];
        const float4 p3 = part[3 * n4 + n];
        const float4 bv = bias4[n & 63];
        float4 r;
        r.x = (p0.x + p1.x) + (p2.x + p3.x) + bv.x;
        r.y = (p0.y + p1.y) + (p2.y + p3.y) + bv.y;
        r.z = (p0.z + p1.z) + (p2.z + p3.z) + bv.z;
        r.w = (p0.w + p1.w) + (p2.w + p3.w) + bv.w;
        out[n] = r;
    }
}

// ---------------------------------------------------------------------------
extern "C" void kernel_launch(void* const* d_in, const int* in_sizes, int n_in,
                              void* d_out, int out_size, void* d_ws, size_t ws_size,
                              hipStream_t stream) {
    const float* x      = (const float*)d_in[0];   // (B, 256) fp32
    const float* coeffs = (const float*)d_in[1];   // (256, 256, 19, 4) fp32
    const float* bias   = (const float*)d_in[2];   // (256,) fp32
    float*       out    = (float*)d_out;           // (B, 256) fp32

    const int B = in_sizes[0] / IN_DIM;            // 1024
    uint4* Ct   = (uint4*)d_ws;                    // 9.96 MB f16 slices
    float* part = (float*)((char*)d_ws + (16u << 20)); // 4 MB

    transpose_pack<<<304, 256, 0, stream>>>((const float4*)coeffs, Ct);

    kan_partial<<<(B / 4) * 8, 256, 0, stream>>>(x, Ct, (float2*)part, B);

    const int n4 = B * OUT_DIM / 4;                // B*64
    kan_reduce<<<(n4 + 255) / 256, 256, 0, stream>>>(
        (const float4*)part, (const float4*)bias, (float4*)out, n4);
}